// Round 6
// baseline (250.627 us; speedup 1.0000x reference)
//
#include <hip/hip_runtime.h>
#include <stdint.h>
#include <math.h>

#define C_DIM 128
#define N_TOK 4096
#define NB 4
#define LOG2E 1.4426950408889634f

typedef __attribute__((ext_vector_type(8))) short bf16x8;
typedef __attribute__((ext_vector_type(4))) short bf16x4;
typedef __attribute__((ext_vector_type(4))) float f32x4;

__device__ __forceinline__ unsigned short f2bf(float f) {
  unsigned u = __builtin_bit_cast(unsigned, f);
  unsigned r = (u + 0x7FFFu + ((u >> 16) & 1u)) >> 16;
  return (unsigned short)r;
}
__device__ __forceinline__ float bf2f(unsigned short h) {
  return __builtin_bit_cast(float, ((unsigned)h) << 16);
}
__device__ __forceinline__ void gload_lds16(const void* g, void* l) {
  __builtin_amdgcn_global_load_lds((const __attribute__((address_space(1))) void*)g,
                                   (__attribute__((address_space(3))) void*)l,
                                   16, 0, 0);
}

// ---------------- Stage 1: conv1x1(c->2c)+BN -> q [b][n][c] bf16, vT [b][c][n] bf16, max|q|^2 ----------------
__global__ __launch_bounds__(256) void proj_in_kernel(
    const float* __restrict__ x, const float* __restrict__ w_inp,
    const float* __restrict__ b_inp, const float* __restrict__ gamma,
    const float* __restrict__ beta, const float* __restrict__ mean,
    const float* __restrict__ var,
    unsigned short* __restrict__ q, unsigned short* __restrict__ vT,
    int* __restrict__ m2bits) {
  __shared__ char smem[36096];
  unsigned short* xh = (unsigned short*)smem;            // [64][136] bf16 hi
  unsigned short* xl = (unsigned short*)(smem + 17408);  // [64][136] bf16 lo
  float* blkred = (float*)(smem + 35840);                // [64]

  const int tid = threadIdx.x;
  const int b = blockIdx.x >> 6;
  const int n0 = (blockIdx.x & 63) << 6;
  const int lane = tid & 63;
  const int wave = tid >> 6;
  const int l15 = lane & 15, lg = lane >> 4;

  {
    const int c = tid >> 1;
    const int j0 = (tid & 1) * 32;
    const float* src = x + ((size_t)b * C_DIM + c) * N_TOK + n0 + j0;
#pragma unroll
    for (int j = 0; j < 32; j += 4) {
      float4 v4 = *(const float4*)(src + j);
#pragma unroll
      for (int e = 0; e < 4; e++) {
        float f = (&v4.x)[e];
        unsigned short hi = f2bf(f);
        unsigned short lo = f2bf(f - bf2f(hi));
        int n = j0 + j + e;
        xh[n * 136 + c] = hi;
        xl[n * 136 + c] = lo;
      }
    }
  }
  __syncthreads();

  f32x4 acc[4][4];
#pragma unroll
  for (int i = 0; i < 4; i++)
#pragma unroll
    for (int j = 0; j < 4; j++) acc[i][j] = {0.f, 0.f, 0.f, 0.f};

#pragma unroll
  for (int ks = 0; ks < 4; ks++) {
    bf16x8 ah[4], al[4];
#pragma unroll
    for (int ot = 0; ot < 4; ot++) {
      const int o = wave * 64 + ot * 16 + l15;
      const float* wp = w_inp + o * C_DIM + ks * 32 + lg * 8;
      float4 w0 = *(const float4*)wp;
      float4 w1 = *(const float4*)(wp + 4);
#pragma unroll
      for (int e = 0; e < 8; e++) {
        float f = (e < 4) ? (&w0.x)[e] : (&w1.x)[e - 4];
        unsigned short hi = f2bf(f);
        ah[ot][e] = (short)hi;
        al[ot][e] = (short)f2bf(f - bf2f(hi));
      }
    }
#pragma unroll
    for (int nt = 0; nt < 4; nt++) {
      const int off = (nt * 16 + l15) * 136 + ks * 32 + lg * 8;
      bf16x8 bh = *(const bf16x8*)(xh + off);
      bf16x8 bl = *(const bf16x8*)(xl + off);
#pragma unroll
      for (int ot = 0; ot < 4; ot++) {
        acc[ot][nt] = __builtin_amdgcn_mfma_f32_16x16x32_bf16(ah[ot], bh, acc[ot][nt], 0, 0, 0);
        acc[ot][nt] = __builtin_amdgcn_mfma_f32_16x16x32_bf16(ah[ot], bl, acc[ot][nt], 0, 0, 0);
        acc[ot][nt] = __builtin_amdgcn_mfma_f32_16x16x32_bf16(al[ot], bh, acc[ot][nt], 0, 0, 0);
      }
    }
  }
  __syncthreads();

  unsigned short* qT = (unsigned short*)smem;             // [64][136]
  unsigned short* vTl = (unsigned short*)(smem + 17408);  // [128][72]

#pragma unroll
  for (int ot = 0; ot < 4; ot++) {
#pragma unroll
    for (int r = 0; r < 4; r++) {
      const int o = wave * 64 + ot * 16 + lg * 4 + r;
      float A = gamma[o] * rsqrtf(var[o] + 1e-5f);
      float Bo = beta[o] + (b_inp[o] - mean[o]) * A;
#pragma unroll
      for (int nt = 0; nt < 4; nt++) {
        float val = acc[ot][nt][r] * A + Bo;
        unsigned short hv = f2bf(val);
        int n = nt * 16 + l15;
        if (wave < 2) {
          qT[n * 136 + o] = hv;
        } else {
          vTl[(o - 128) * 72 + n] = hv;
        }
      }
    }
  }
  __syncthreads();
  {
    int j = tid >> 2, c0 = (tid & 3) * 32;
    unsigned short* dst = q + ((size_t)b * N_TOK + n0 + j) * C_DIM + c0;
    const unsigned short* s = qT + j * 136 + c0;
#pragma unroll
    for (int i = 0; i < 32; i += 8) *(bf16x8*)(dst + i) = *(const bf16x8*)(s + i);
  }
  {
    int c = tid >> 1, h = (tid & 1) * 32;
    unsigned short* dst = vT + ((size_t)b * C_DIM + c) * N_TOK + n0 + h;
    const unsigned short* s = vTl + c * 72 + h;
#pragma unroll
    for (int i = 0; i < 32; i += 8) *(bf16x8*)(dst + i) = *(const bf16x8*)(s + i);
  }
  // ---- row-norm^2 max -> global atomic (for fixed-m softmax bound) ----
  {
    int row = tid >> 2, qn = tid & 3;
    const unsigned short* qr = qT + row * 136 + qn * 32;
    float s = 0.f;
#pragma unroll
    for (int i = 0; i < 32; i++) {
      float f = bf2f(qr[i]);
      s = fmaf(f, f, s);
    }
    s += __shfl_xor(s, 1);
    s += __shfl_xor(s, 2);
    if ((tid & 3) == 0) blkred[row] = s;
    __syncthreads();
    if (tid < 64) {
      float v = blkred[tid];
      v = fmaxf(v, __shfl_xor(v, 1));
      v = fmaxf(v, __shfl_xor(v, 2));
      v = fmaxf(v, __shfl_xor(v, 4));
      v = fmaxf(v, __shfl_xor(v, 8));
      v = fmaxf(v, __shfl_xor(v, 16));
      v = fmaxf(v, __shfl_xor(v, 32));
      if (tid == 0) atomicMax(m2bits, __float_as_int(v));
    }
  }
}

// ---------------- Stage 2: attention (fixed-m) + fused project_out ----------------
// 1024 blocks x 16 q-rows, 4 waves: QK split by key-quarter (kq=wave), PV split by
// channel-pair (no PV merge). P exchanged via double-buffered LDS pbuf; ONE barrier
// per K-tile. LDS 37.9KB -> 4 blocks/CU (16 waves/CU). Sweep2: QK recompute + store.
__global__ __launch_bounds__(256, 4) void attn_kernel(
    const unsigned short* __restrict__ q, const unsigned short* __restrict__ vT,
    const float* __restrict__ w_out, const float* __restrict__ b_out,
    float* __restrict__ yout, float* __restrict__ atn,
    const float* __restrict__ m2ptr) {
  __shared__ char smem[37888];
  // [0,32768): K dbuf (2 x 16KB); reused post-loop as yl/ol proj scratch
  // [32768,37376): pbuf [2][16][72] bf16
  // [37376,37632): statsL [64] f32

  const int tid = threadIdx.x;
  const int lane = tid & 63;
  const int kq = tid >> 6;  // wave = key-quarter for QK, channel-pair for PV
  const int l15 = lane & 15, lg = lane >> 4, l7 = lane & 7;
  // XCD swizzle: 1024 blocks, 8 XCDs, 128 consecutive logical blocks per XCD
  const int bid = (int)((blockIdx.x & 7) * 128 + (blockIdx.x >> 3));
  const int b = bid >> 8;
  const int row0 = (bid & 255) << 4;

  const unsigned short* qb = q + (size_t)b * N_TOK * C_DIM;
  const unsigned short* vb = vT + (size_t)b * C_DIM * N_TOK;

  const float scale = 0.08838834764831845f;  // 1/sqrt(128)
  const float ke = scale * LOG2E;
  const float nmk = -(m2ptr[0]) * ke;

  // Q fragments (B operand, col = l15 = qrow)
  bf16x8 qf[4];
#pragma unroll
  for (int ks = 0; ks < 4; ks++)
    qf[ks] = *(const bf16x8*)(qb + (size_t)(row0 + l15) * C_DIM + ks * 32 + lg * 8);

  int koff[4];
#pragma unroll
  for (int ks = 0; ks < 4; ks++) koff[ks] = (ks * 64 + lg * 16) ^ (l7 * 16);
  const int kqbase = kq * 4096 + l15 * 256;  // this wave's key strip base (bytes)

  auto stageK = [&](int kt, int buf) {
    char* base = smem + buf * 16384;
#pragma unroll
    for (int i = 0; i < 4; i++) {
      int lin = i * 256 + tid;
      int key = lin >> 4;
      int c = ((lin & 15) * 8) ^ ((key & 7) * 8);
      gload_lds16(qb + (size_t)(kt * 64 + key) * C_DIM + c, base + lin * 16);
    }
  };

  unsigned short* pbw = (unsigned short*)(smem + 32768) + l15 * 72 + kq * 16 + lg * 4;
  const char* parb = smem + 32768 + l15 * 144;
  float* statsL = (float*)(smem + 37376);

  // V lane bases for this wave's two channel groups
  const unsigned short* vl0 = vb + (size_t)((kq * 2 + 0) * 16 + l15) * N_TOK + lg * 8;
  const unsigned short* vl1 = vb + (size_t)((kq * 2 + 1) * 16 + l15) * N_TOK + lg * 8;

  float lpart = 0.f;
  f32x4 yacc[2];
  yacc[0] = {0.f, 0.f, 0.f, 0.f};
  yacc[1] = {0.f, 0.f, 0.f, 0.f};

  bf16x8 vA[2][2], vB[2][2];  // [ctl][ks2]
  stageK(0, 0);
#pragma unroll
  for (int ks2 = 0; ks2 < 2; ks2++) {
    vA[0][ks2] = *(const bf16x8*)(vl0 + ks2 * 32);
    vA[1][ks2] = *(const bf16x8*)(vl1 + ks2 * 32);
  }
  __syncthreads();

  auto sweep1_iter = [&](int kt, bf16x8(&vc)[2][2], bf16x8(&vn)[2][2]) {
    const char* kb = smem + (kt & 1) * 16384;
    f32x4 acc = {0.f, 0.f, 0.f, 0.f};
#pragma unroll
    for (int ks = 0; ks < 4; ks++) {
      bf16x8 ak = *(const bf16x8*)(kb + kqbase + koff[ks]);
      acc = __builtin_amdgcn_mfma_f32_16x16x32_bf16(ak, qf[ks], acc, 0, 0, 0);
    }
    bf16x4 pk;
#pragma unroll
    for (int r = 0; r < 4; r++) {
      float p = __builtin_amdgcn_exp2f(fmaf(acc[r], ke, nmk));
      lpart += p;
      pk[r] = (short)f2bf(p);
    }
    *(bf16x4*)(pbw + (kt & 1) * 1152) = pk;  // 1152 shorts = 2304 B
    if (kt + 1 < 64) stageK(kt + 1, (kt + 1) & 1);
    __syncthreads();
    // PV from shared pbuf (all 4 key-quarters) for this wave's 2 channel groups
    const char* pbt = parb + (kt & 1) * 2304;
#pragma unroll
    for (int ks2 = 0; ks2 < 2; ks2++) {
      bf16x8 ap = *(const bf16x8*)(pbt + ks2 * 64 + lg * 16);
      yacc[0] = __builtin_amdgcn_mfma_f32_16x16x32_bf16(ap, vc[0][ks2], yacc[0], 0, 0, 0);
      yacc[1] = __builtin_amdgcn_mfma_f32_16x16x32_bf16(ap, vc[1][ks2], yacc[1], 0, 0, 0);
    }
    if (kt + 1 < 64) {
      const unsigned short* v0 = vl0 + (size_t)(kt + 1) * 64;
      const unsigned short* v1 = vl1 + (size_t)(kt + 1) * 64;
#pragma unroll
      for (int ks2 = 0; ks2 < 2; ks2++) {
        vn[0][ks2] = *(const bf16x8*)(v0 + ks2 * 32);
        vn[1][ks2] = *(const bf16x8*)(v1 + ks2 * 32);
      }
    }
  };

  for (int kt = 0; kt < 64; kt += 2) {
    sweep1_iter(kt, vA, vB);
    sweep1_iter(kt + 1, vB, vA);
  }

  // ---- merge l across lanes and key-quarters ----
  lpart += __shfl_xor(lpart, 16);
  lpart += __shfl_xor(lpart, 32);
  if (lg == 0) statsL[kq * 16 + l15] = lpart;
  __syncthreads();

  float invl_r[4];
#pragma unroll
  for (int r = 0; r < 4; r++) {
    const int row = lg * 4 + r;
    invl_r[r] = 1.0f / (statsL[row] + statsL[16 + row] + statsL[32 + row] + statsL[48 + row]);
  }
  const float invl2 =
      1.0f / (statsL[l15] + statsL[16 + l15] + statsL[32 + l15] + statsL[48 + l15]);

  // ---- fused project_out (kbuf area as scratch) ----
  __syncthreads();  // kbuf reads done
  {
    unsigned short* yl = (unsigned short*)smem;  // [16][136] bf16
    float* ol = (float*)(smem + 8192);           // [128][20] f32
#pragma unroll
    for (int ctl = 0; ctl < 2; ctl++)
#pragma unroll
      for (int r = 0; r < 4; r++)
        yl[(lg * 4 + r) * 136 + (kq * 2 + ctl) * 16 + l15] = f2bf(yacc[ctl][r] * invl_r[r]);
    __syncthreads();

    bf16x8 af[4];
#pragma unroll
    for (int ks = 0; ks < 4; ks++)
      af[ks] = *(const bf16x8*)(yl + l15 * 136 + ks * 32 + lg * 8);

#pragma unroll
    for (int cotl = 0; cotl < 2; cotl++) {
      const int cot = kq * 2 + cotl;
      f32x4 oacc = {0.f, 0.f, 0.f, 0.f};
#pragma unroll
      for (int ks = 0; ks < 4; ks++) {
        const float* wp = w_out + (cot * 16 + l15) * C_DIM + ks * 32 + lg * 8;
        float4 w0 = *(const float4*)wp;
        float4 w1 = *(const float4*)(wp + 4);
        bf16x8 bw;
#pragma unroll
        for (int e = 0; e < 8; e++) bw[e] = (short)f2bf((e < 4) ? (&w0.x)[e] : (&w1.x)[e - 4]);
        oacc = __builtin_amdgcn_mfma_f32_16x16x32_bf16(af[ks], bw, oacc, 0, 0, 0);
      }
      float bo = b_out[cot * 16 + l15];
#pragma unroll
      for (int r = 0; r < 4; r++) ol[(cot * 16 + l15) * 20 + lg * 4 + r] = oacc[r] + bo;
    }
    __syncthreads();
    {
      const int co = tid >> 1;
      const int r0 = (tid & 1) * 8;
      float* dst = yout + ((size_t)b * C_DIM + co) * N_TOK + row0 + r0;
      const float* s = ol + co * 20 + r0;
      *(float4*)dst = *(const float4*)s;
      *(float4*)(dst + 4) = *(const float4*)(s + 4);
    }
  }
  __syncthreads();  // scratch done before kbuf staging reuse

  // ---- Sweep 2: recompute S^T, store atn = p'/l (f32x4 per lane) ----
  stageK(0, 0);
  __syncthreads();
  float* atnp = atn + ((size_t)b * N_TOK + row0 + l15) * N_TOK + kq * 16 + lg * 4;
  for (int kt = 0; kt < 64; kt++) {
    const char* kb = smem + (kt & 1) * 16384;
    f32x4 acc = {0.f, 0.f, 0.f, 0.f};
#pragma unroll
    for (int ks = 0; ks < 4; ks++) {
      bf16x8 ak = *(const bf16x8*)(kb + kqbase + koff[ks]);
      acc = __builtin_amdgcn_mfma_f32_16x16x32_bf16(ak, qf[ks], acc, 0, 0, 0);
    }
    f32x4 o;
#pragma unroll
    for (int r = 0; r < 4; r++)
      o[r] = __builtin_amdgcn_exp2f(fmaf(acc[r], ke, nmk)) * invl2;
    __builtin_nontemporal_store(o, (f32x4*)(atnp + (size_t)kt * 64));
    if (kt + 1 < 64) stageK(kt + 1, (kt + 1) & 1);
    __syncthreads();
  }
}

extern "C" void kernel_launch(void* const* d_in, const int* in_sizes, int n_in,
                              void* d_out, int out_size, void* d_ws, size_t ws_size,
                              hipStream_t stream) {
  const float* x = (const float*)d_in[0];
  const float* w_inp = (const float*)d_in[1];
  const float* b_inp = (const float*)d_in[2];
  const float* gamma = (const float*)d_in[3];
  const float* beta = (const float*)d_in[4];
  const float* mean = (const float*)d_in[5];
  const float* var = (const float*)d_in[6];
  const float* w_out = (const float*)d_in[7];
  const float* b_out = (const float*)d_in[8];

  float* out = (float*)d_out;
  float* yout = out;                              // [4][128][4096]
  float* atn = out + (size_t)NB * C_DIM * N_TOK;  // [4][4096][4096]

  unsigned short* q = (unsigned short*)d_ws;            // [4][4096][128] bf16
  unsigned short* vT = q + (size_t)NB * N_TOK * C_DIM;  // [4][128][4096] bf16
  int* m2bits = (int*)(vT + (size_t)NB * C_DIM * N_TOK);

  hipMemsetAsync(m2bits, 0, 4, stream);
  proj_in_kernel<<<256, 256, 0, stream>>>(x, w_inp, b_inp, gamma, beta, mean, var, q, vT, m2bits);
  attn_kernel<<<1024, 256, 0, stream>>>(q, vT, w_out, b_out, yout, atn, (const float*)m2bits);
}

// Round 7
// 241.097 us; speedup vs baseline: 1.0395x; 1.0395x over previous
//
#include <hip/hip_runtime.h>
#include <stdint.h>
#include <math.h>

#define C_DIM 128
#define N_TOK 4096
#define NB 4
#define LOG2E 1.4426950408889634f

typedef __attribute__((ext_vector_type(8))) short bf16x8;
typedef __attribute__((ext_vector_type(4))) short bf16x4;
typedef __attribute__((ext_vector_type(4))) float f32x4;

#define WAIT_VM(N) asm volatile("s_waitcnt vmcnt(" #N ")" ::: "memory")
#define WAIT_LGKM0 asm volatile("s_waitcnt lgkmcnt(0)" ::: "memory")
#define SBAR() __builtin_amdgcn_s_barrier()
#define SCHED_FENCE() __builtin_amdgcn_sched_barrier(0)

__device__ __forceinline__ unsigned short f2bf(float f) {
  unsigned u = __builtin_bit_cast(unsigned, f);
  unsigned r = (u + 0x7FFFu + ((u >> 16) & 1u)) >> 16;
  return (unsigned short)r;
}
__device__ __forceinline__ float bf2f(unsigned short h) {
  return __builtin_bit_cast(float, ((unsigned)h) << 16);
}
__device__ __forceinline__ void gload_lds16(const void* g, void* l) {
  __builtin_amdgcn_global_load_lds((const __attribute__((address_space(1))) void*)g,
                                   (__attribute__((address_space(3))) void*)l,
                                   16, 0, 0);
}

// ---------------- Stage 1: conv1x1(c->2c)+BN -> q [b][n][c] bf16, vT [b][c][n] bf16, max|q|^2 ----------------
__global__ __launch_bounds__(256) void proj_in_kernel(
    const float* __restrict__ x, const float* __restrict__ w_inp,
    const float* __restrict__ b_inp, const float* __restrict__ gamma,
    const float* __restrict__ beta, const float* __restrict__ mean,
    const float* __restrict__ var,
    unsigned short* __restrict__ q, unsigned short* __restrict__ vT,
    int* __restrict__ m2bits) {
  __shared__ char smem[36096];
  unsigned short* xh = (unsigned short*)smem;            // [64][136] bf16 hi
  unsigned short* xl = (unsigned short*)(smem + 17408);  // [64][136] bf16 lo
  float* blkred = (float*)(smem + 35840);                // [64]

  const int tid = threadIdx.x;
  const int b = blockIdx.x >> 6;
  const int n0 = (blockIdx.x & 63) << 6;
  const int lane = tid & 63;
  const int wave = tid >> 6;
  const int l15 = lane & 15, lg = lane >> 4;

  {
    const int c = tid >> 1;
    const int j0 = (tid & 1) * 32;
    const float* src = x + ((size_t)b * C_DIM + c) * N_TOK + n0 + j0;
#pragma unroll
    for (int j = 0; j < 32; j += 4) {
      float4 v4 = *(const float4*)(src + j);
#pragma unroll
      for (int e = 0; e < 4; e++) {
        float f = (&v4.x)[e];
        unsigned short hi = f2bf(f);
        unsigned short lo = f2bf(f - bf2f(hi));
        int n = j0 + j + e;
        xh[n * 136 + c] = hi;
        xl[n * 136 + c] = lo;
      }
    }
  }
  __syncthreads();

  f32x4 acc[4][4];
#pragma unroll
  for (int i = 0; i < 4; i++)
#pragma unroll
    for (int j = 0; j < 4; j++) acc[i][j] = {0.f, 0.f, 0.f, 0.f};

#pragma unroll
  for (int ks = 0; ks < 4; ks++) {
    bf16x8 ah[4], al[4];
#pragma unroll
    for (int ot = 0; ot < 4; ot++) {
      const int o = wave * 64 + ot * 16 + l15;
      const float* wp = w_inp + o * C_DIM + ks * 32 + lg * 8;
      float4 w0 = *(const float4*)wp;
      float4 w1 = *(const float4*)(wp + 4);
#pragma unroll
      for (int e = 0; e < 8; e++) {
        float f = (e < 4) ? (&w0.x)[e] : (&w1.x)[e - 4];
        unsigned short hi = f2bf(f);
        ah[ot][e] = (short)hi;
        al[ot][e] = (short)f2bf(f - bf2f(hi));
      }
    }
#pragma unroll
    for (int nt = 0; nt < 4; nt++) {
      const int off = (nt * 16 + l15) * 136 + ks * 32 + lg * 8;
      bf16x8 bh = *(const bf16x8*)(xh + off);
      bf16x8 bl = *(const bf16x8*)(xl + off);
#pragma unroll
      for (int ot = 0; ot < 4; ot++) {
        acc[ot][nt] = __builtin_amdgcn_mfma_f32_16x16x32_bf16(ah[ot], bh, acc[ot][nt], 0, 0, 0);
        acc[ot][nt] = __builtin_amdgcn_mfma_f32_16x16x32_bf16(ah[ot], bl, acc[ot][nt], 0, 0, 0);
        acc[ot][nt] = __builtin_amdgcn_mfma_f32_16x16x32_bf16(al[ot], bh, acc[ot][nt], 0, 0, 0);
      }
    }
  }
  __syncthreads();

  unsigned short* qT = (unsigned short*)smem;             // [64][136]
  unsigned short* vTl = (unsigned short*)(smem + 17408);  // [128][72]

#pragma unroll
  for (int ot = 0; ot < 4; ot++) {
#pragma unroll
    for (int r = 0; r < 4; r++) {
      const int o = wave * 64 + ot * 16 + lg * 4 + r;
      float A = gamma[o] * rsqrtf(var[o] + 1e-5f);
      float Bo = beta[o] + (b_inp[o] - mean[o]) * A;
#pragma unroll
      for (int nt = 0; nt < 4; nt++) {
        float val = acc[ot][nt][r] * A + Bo;
        unsigned short hv = f2bf(val);
        int n = nt * 16 + l15;
        if (wave < 2) {
          qT[n * 136 + o] = hv;
        } else {
          vTl[(o - 128) * 72 + n] = hv;
        }
      }
    }
  }
  __syncthreads();
  {
    int j = tid >> 2, c0 = (tid & 3) * 32;
    unsigned short* dst = q + ((size_t)b * N_TOK + n0 + j) * C_DIM + c0;
    const unsigned short* s = qT + j * 136 + c0;
#pragma unroll
    for (int i = 0; i < 32; i += 8) *(bf16x8*)(dst + i) = *(const bf16x8*)(s + i);
  }
  {
    int c = tid >> 1, h = (tid & 1) * 32;
    unsigned short* dst = vT + ((size_t)b * C_DIM + c) * N_TOK + n0 + h;
    const unsigned short* s = vTl + c * 72 + h;
#pragma unroll
    for (int i = 0; i < 32; i += 8) *(bf16x8*)(dst + i) = *(const bf16x8*)(s + i);
  }
  // ---- row-norm^2 max -> global atomic (for fixed-m softmax bound) ----
  {
    int row = tid >> 2, qn = tid & 3;
    const unsigned short* qr = qT + row * 136 + qn * 32;
    float s = 0.f;
#pragma unroll
    for (int i = 0; i < 32; i++) {
      float f = bf2f(qr[i]);
      s = fmaf(f, f, s);
    }
    s += __shfl_xor(s, 1);
    s += __shfl_xor(s, 2);
    if ((tid & 3) == 0) blkred[row] = s;
    __syncthreads();
    if (tid < 64) {
      float v = blkred[tid];
      v = fmaxf(v, __shfl_xor(v, 1));
      v = fmaxf(v, __shfl_xor(v, 2));
      v = fmaxf(v, __shfl_xor(v, 4));
      v = fmaxf(v, __shfl_xor(v, 8));
      v = fmaxf(v, __shfl_xor(v, 16));
      v = fmaxf(v, __shfl_xor(v, 32));
      if (tid == 0) atomicMax(m2bits, __float_as_int(v));
    }
  }
}

// ---------------- Stage 2: attention (fixed-m) + fused project_out ----------------
// r6 geometry (1024 blocks x 16 rows, 4 waves, kq split; PV channel-pair, no merge)
// + counted-vmcnt schedule: per iter issue exactly 8 VMEM/wave (sweep1) or 4+1
// (sweep2), wait vmcnt(N) for the PREVIOUS iteration's loads only, raw s_barrier.
// No drain-to-zero in the main loops; stores stay in flight.
__global__ __launch_bounds__(256, 4) void attn_kernel(
    const unsigned short* __restrict__ q, const unsigned short* __restrict__ vT,
    const float* __restrict__ w_out, const float* __restrict__ b_out,
    float* __restrict__ yout, float* __restrict__ atn,
    const float* __restrict__ m2ptr) {
  __shared__ char smem[37888];
  // [0,32768): K dbuf (2 x 16KB); reused post-loop as yl/ol proj scratch
  // [32768,37376): pbuf [2][16][72] bf16
  // [37376,37632): statsL [64] f32

  const int tid = threadIdx.x;
  const int lane = tid & 63;
  const int kq = tid >> 6;  // wave = key-quarter for QK, channel-pair for PV
  const int l15 = lane & 15, lg = lane >> 4, l7 = lane & 7;
  const int bid = (int)((blockIdx.x & 7) * 128 + (blockIdx.x >> 3));
  const int b = bid >> 8;
  const int row0 = (bid & 255) << 4;

  const unsigned short* qb = q + (size_t)b * N_TOK * C_DIM;
  const unsigned short* vb = vT + (size_t)b * C_DIM * N_TOK;

  const float scale = 0.08838834764831845f;  // 1/sqrt(128)
  const float ke = scale * LOG2E;
  const float nmk = -(m2ptr[0]) * ke;

  bf16x8 qf[4];
#pragma unroll
  for (int ks = 0; ks < 4; ks++)
    qf[ks] = *(const bf16x8*)(qb + (size_t)(row0 + l15) * C_DIM + ks * 32 + lg * 8);

  int koff[4];
#pragma unroll
  for (int ks = 0; ks < 4; ks++) koff[ks] = (ks * 64 + lg * 16) ^ (l7 * 16);
  const int kqbase = kq * 4096 + l15 * 256;

  auto stageK = [&](int kt, int buf) {
    char* base = smem + buf * 16384;
#pragma unroll
    for (int i = 0; i < 4; i++) {
      int lin = i * 256 + tid;
      int key = lin >> 4;
      int c = ((lin & 15) * 8) ^ ((key & 7) * 8);
      gload_lds16(qb + (size_t)(kt * 64 + key) * C_DIM + c, base + lin * 16);
    }
  };

  unsigned short* pbw = (unsigned short*)(smem + 32768) + l15 * 72 + kq * 16 + lg * 4;
  const char* parb = smem + 32768 + l15 * 144;
  float* statsL = (float*)(smem + 37376);

  const unsigned short* vl0 = vb + (size_t)((kq * 2 + 0) * 16 + l15) * N_TOK + lg * 8;
  const unsigned short* vl1 = vb + (size_t)((kq * 2 + 1) * 16 + l15) * N_TOK + lg * 8;

  float lpart = 0.f;
  f32x4 yacc[2];
  yacc[0] = {0.f, 0.f, 0.f, 0.f};
  yacc[1] = {0.f, 0.f, 0.f, 0.f};

  bf16x8 vA[2][2], vB[2][2];
  // prologue: stage K(0), load V(0); full drain once
  stageK(0, 0);
#pragma unroll
  for (int ks2 = 0; ks2 < 2; ks2++) {
    vA[0][ks2] = *(const bf16x8*)(vl0 + ks2 * 32);
    vA[1][ks2] = *(const bf16x8*)(vl1 + ks2 * 32);
  }
  WAIT_VM(0);
  SBAR();
  SCHED_FENCE();

  auto sweep1_iter = [&](int kt, bf16x8(&vc)[2][2], bf16x8(&vn)[2][2]) {
    // issue next tile's loads: exactly 8 VMEM ops per wave
    if (kt + 1 < 64) {
      stageK(kt + 1, (kt + 1) & 1);
      const unsigned short* v0 = vl0 + (size_t)(kt + 1) * 64;
      const unsigned short* v1 = vl1 + (size_t)(kt + 1) * 64;
#pragma unroll
      for (int ks2 = 0; ks2 < 2; ks2++) {
        vn[0][ks2] = *(const bf16x8*)(v0 + ks2 * 32);
        vn[1][ks2] = *(const bf16x8*)(v1 + ks2 * 32);
      }
      WAIT_VM(8);  // waits for tile kt's 8 loads (issued last iter); keeps 8 in flight
    } else {
      WAIT_VM(0);
    }
    SBAR();  // tile kt staged for all waves
    SCHED_FENCE();
    const char* kb = smem + (kt & 1) * 16384;
    f32x4 acc = {0.f, 0.f, 0.f, 0.f};
#pragma unroll
    for (int ks = 0; ks < 4; ks++) {
      bf16x8 ak = *(const bf16x8*)(kb + kqbase + koff[ks]);
      acc = __builtin_amdgcn_mfma_f32_16x16x32_bf16(ak, qf[ks], acc, 0, 0, 0);
    }
    bf16x4 pk;
#pragma unroll
    for (int r = 0; r < 4; r++) {
      float p = __builtin_amdgcn_exp2f(fmaf(acc[r], ke, nmk));
      lpart += p;
      pk[r] = (short)f2bf(p);
    }
    *(bf16x4*)(pbw + (kt & 1) * 1152) = pk;
    WAIT_LGKM0;
    SBAR();  // P visible to all waves
    SCHED_FENCE();
    const char* pbt = parb + (kt & 1) * 2304;
#pragma unroll
    for (int ks2 = 0; ks2 < 2; ks2++) {
      bf16x8 ap = *(const bf16x8*)(pbt + ks2 * 64 + lg * 16);
      yacc[0] = __builtin_amdgcn_mfma_f32_16x16x32_bf16(ap, vc[0][ks2], yacc[0], 0, 0, 0);
      yacc[1] = __builtin_amdgcn_mfma_f32_16x16x32_bf16(ap, vc[1][ks2], yacc[1], 0, 0, 0);
    }
  };

  for (int kt = 0; kt < 64; kt += 2) {
    sweep1_iter(kt, vA, vB);
    sweep1_iter(kt + 1, vB, vA);
  }

  // ---- merge l across lanes and key-quarters ----
  lpart += __shfl_xor(lpart, 16);
  lpart += __shfl_xor(lpart, 32);
  if (lg == 0) statsL[kq * 16 + l15] = lpart;
  __syncthreads();

  float invl_r[4];
#pragma unroll
  for (int r = 0; r < 4; r++) {
    const int row = lg * 4 + r;
    invl_r[r] = 1.0f / (statsL[row] + statsL[16 + row] + statsL[32 + row] + statsL[48 + row]);
  }
  const float invl2 =
      1.0f / (statsL[l15] + statsL[16 + l15] + statsL[32 + l15] + statsL[48 + l15]);

  // ---- fused project_out (kbuf area as scratch) ----
  __syncthreads();
  {
    unsigned short* yl = (unsigned short*)smem;  // [16][136] bf16
    float* ol = (float*)(smem + 8192);           // [128][20] f32
#pragma unroll
    for (int ctl = 0; ctl < 2; ctl++)
#pragma unroll
      for (int r = 0; r < 4; r++)
        yl[(lg * 4 + r) * 136 + (kq * 2 + ctl) * 16 + l15] = f2bf(yacc[ctl][r] * invl_r[r]);
    __syncthreads();

    bf16x8 af[4];
#pragma unroll
    for (int ks = 0; ks < 4; ks++)
      af[ks] = *(const bf16x8*)(yl + l15 * 136 + ks * 32 + lg * 8);

#pragma unroll
    for (int cotl = 0; cotl < 2; cotl++) {
      const int cot = kq * 2 + cotl;
      f32x4 oacc = {0.f, 0.f, 0.f, 0.f};
#pragma unroll
      for (int ks = 0; ks < 4; ks++) {
        const float* wp = w_out + (cot * 16 + l15) * C_DIM + ks * 32 + lg * 8;
        float4 w0 = *(const float4*)wp;
        float4 w1 = *(const float4*)(wp + 4);
        bf16x8 bw;
#pragma unroll
        for (int e = 0; e < 8; e++) bw[e] = (short)f2bf((e < 4) ? (&w0.x)[e] : (&w1.x)[e - 4]);
        oacc = __builtin_amdgcn_mfma_f32_16x16x32_bf16(af[ks], bw, oacc, 0, 0, 0);
      }
      float bo = b_out[cot * 16 + l15];
#pragma unroll
      for (int r = 0; r < 4; r++) ol[(cot * 16 + l15) * 20 + lg * 4 + r] = oacc[r] + bo;
    }
    __syncthreads();
    {
      const int co = tid >> 1;
      const int r0 = (tid & 1) * 8;
      float* dst = yout + ((size_t)b * C_DIM + co) * N_TOK + row0 + r0;
      const float* s = ol + co * 20 + r0;
      *(float4*)dst = *(const float4*)s;
      *(float4*)(dst + 4) = *(const float4*)(s + 4);
    }
  }
  __syncthreads();  // scratch done before kbuf staging reuse

  // ---- Sweep 2: recompute S^T, store atn = p'/l; counted vmcnt keeps stores in flight ----
  stageK(0, 0);
  WAIT_VM(0);
  SBAR();
  SCHED_FENCE();
  float* atnp = atn + ((size_t)b * N_TOK + row0 + l15) * N_TOK + kq * 16 + lg * 4;
  for (int kt = 0; kt < 64; kt++) {
    if (kt + 1 < 64) {
      stageK(kt + 1, (kt + 1) & 1);  // 4 VMEM
      WAIT_VM(5);                    // waits tile kt's K loads; prev store stays in flight
    } else {
      WAIT_VM(1);  // all K loads done; newest store may remain in flight
    }
    SBAR();
    SCHED_FENCE();
    const char* kb = smem + (kt & 1) * 16384;
    f32x4 acc = {0.f, 0.f, 0.f, 0.f};
#pragma unroll
    for (int ks = 0; ks < 4; ks++) {
      bf16x8 ak = *(const bf16x8*)(kb + kqbase + koff[ks]);
      acc = __builtin_amdgcn_mfma_f32_16x16x32_bf16(ak, qf[ks], acc, 0, 0, 0);
    }
    f32x4 o;
#pragma unroll
    for (int r = 0; r < 4; r++)
      o[r] = __builtin_amdgcn_exp2f(fmaf(acc[r], ke, nmk)) * invl2;
    *(f32x4*)(atnp + (size_t)kt * 64) = o;  // plain store (L2 write-combining)
    SBAR();  // keep waves phase-locked so buf^1 overwrite can't outrun slow readers
    SCHED_FENCE();
  }
}

extern "C" void kernel_launch(void* const* d_in, const int* in_sizes, int n_in,
                              void* d_out, int out_size, void* d_ws, size_t ws_size,
                              hipStream_t stream) {
  const float* x = (const float*)d_in[0];
  const float* w_inp = (const float*)d_in[1];
  const float* b_inp = (const float*)d_in[2];
  const float* gamma = (const float*)d_in[3];
  const float* beta = (const float*)d_in[4];
  const float* mean = (const float*)d_in[5];
  const float* var = (const float*)d_in[6];
  const float* w_out = (const float*)d_in[7];
  const float* b_out = (const float*)d_in[8];

  float* out = (float*)d_out;
  float* yout = out;                              // [4][128][4096]
  float* atn = out + (size_t)NB * C_DIM * N_TOK;  // [4][4096][4096]

  unsigned short* q = (unsigned short*)d_ws;            // [4][4096][128] bf16
  unsigned short* vT = q + (size_t)NB * N_TOK * C_DIM;  // [4][128][4096] bf16
  int* m2bits = (int*)(vT + (size_t)NB * C_DIM * N_TOK);

  hipMemsetAsync(m2bits, 0, 4, stream);
  proj_in_kernel<<<256, 256, 0, stream>>>(x, w_inp, b_inp, gamma, beta, mean, var, q, vT, m2bits);
  attn_kernel<<<1024, 256, 0, stream>>>(q, vT, w_out, b_out, yout, atn, (const float*)m2bits);
}

// Round 8
// 238.438 us; speedup vs baseline: 1.0511x; 1.0112x over previous
//
#include <hip/hip_runtime.h>
#include <stdint.h>
#include <math.h>

#define C_DIM 128
#define N_TOK 4096
#define NB 4
#define LOG2E 1.4426950408889634f

typedef __attribute__((ext_vector_type(8))) short bf16x8;
typedef __attribute__((ext_vector_type(4))) short bf16x4;
typedef __attribute__((ext_vector_type(4))) float f32x4;

#define WAIT_VM(N) asm volatile("s_waitcnt vmcnt(" #N ")" ::: "memory")
#define WAIT_LGKM0 asm volatile("s_waitcnt lgkmcnt(0)" ::: "memory")
#define SBAR() __builtin_amdgcn_s_barrier()
#define SCHED_FENCE() __builtin_amdgcn_sched_barrier(0)

__device__ __forceinline__ unsigned short f2bf(float f) {
  unsigned u = __builtin_bit_cast(unsigned, f);
  unsigned r = (u + 0x7FFFu + ((u >> 16) & 1u)) >> 16;
  return (unsigned short)r;
}
__device__ __forceinline__ float bf2f(unsigned short h) {
  return __builtin_bit_cast(float, ((unsigned)h) << 16);
}
__device__ __forceinline__ void gload_lds16(const void* g, void* l) {
  __builtin_amdgcn_global_load_lds((const __attribute__((address_space(1))) void*)g,
                                   (__attribute__((address_space(3))) void*)l,
                                   16, 0, 0);
}

// ---------------- Stage 1: conv1x1(c->2c)+BN -> q [b][n][c] bf16, vT [b][c][n] bf16, max|q|^2 ----------------
__global__ __launch_bounds__(256) void proj_in_kernel(
    const float* __restrict__ x, const float* __restrict__ w_inp,
    const float* __restrict__ b_inp, const float* __restrict__ gamma,
    const float* __restrict__ beta, const float* __restrict__ mean,
    const float* __restrict__ var,
    unsigned short* __restrict__ q, unsigned short* __restrict__ vT,
    int* __restrict__ m2bits) {
  __shared__ char smem[36096];
  unsigned short* xh = (unsigned short*)smem;            // [64][136] bf16 hi
  unsigned short* xl = (unsigned short*)(smem + 17408);  // [64][136] bf16 lo
  float* blkred = (float*)(smem + 35840);                // [64]

  const int tid = threadIdx.x;
  const int b = blockIdx.x >> 6;
  const int n0 = (blockIdx.x & 63) << 6;
  const int lane = tid & 63;
  const int wave = tid >> 6;
  const int l15 = lane & 15, lg = lane >> 4;

  {
    const int c = tid >> 1;
    const int j0 = (tid & 1) * 32;
    const float* src = x + ((size_t)b * C_DIM + c) * N_TOK + n0 + j0;
#pragma unroll
    for (int j = 0; j < 32; j += 4) {
      float4 v4 = *(const float4*)(src + j);
#pragma unroll
      for (int e = 0; e < 4; e++) {
        float f = (&v4.x)[e];
        unsigned short hi = f2bf(f);
        unsigned short lo = f2bf(f - bf2f(hi));
        int n = j0 + j + e;
        xh[n * 136 + c] = hi;
        xl[n * 136 + c] = lo;
      }
    }
  }
  __syncthreads();

  f32x4 acc[4][4];
#pragma unroll
  for (int i = 0; i < 4; i++)
#pragma unroll
    for (int j = 0; j < 4; j++) acc[i][j] = {0.f, 0.f, 0.f, 0.f};

#pragma unroll
  for (int ks = 0; ks < 4; ks++) {
    bf16x8 ah[4], al[4];
#pragma unroll
    for (int ot = 0; ot < 4; ot++) {
      const int o = wave * 64 + ot * 16 + l15;
      const float* wp = w_inp + o * C_DIM + ks * 32 + lg * 8;
      float4 w0 = *(const float4*)wp;
      float4 w1 = *(const float4*)(wp + 4);
#pragma unroll
      for (int e = 0; e < 8; e++) {
        float f = (e < 4) ? (&w0.x)[e] : (&w1.x)[e - 4];
        unsigned short hi = f2bf(f);
        ah[ot][e] = (short)hi;
        al[ot][e] = (short)f2bf(f - bf2f(hi));
      }
    }
#pragma unroll
    for (int nt = 0; nt < 4; nt++) {
      const int off = (nt * 16 + l15) * 136 + ks * 32 + lg * 8;
      bf16x8 bh = *(const bf16x8*)(xh + off);
      bf16x8 bl = *(const bf16x8*)(xl + off);
#pragma unroll
      for (int ot = 0; ot < 4; ot++) {
        acc[ot][nt] = __builtin_amdgcn_mfma_f32_16x16x32_bf16(ah[ot], bh, acc[ot][nt], 0, 0, 0);
        acc[ot][nt] = __builtin_amdgcn_mfma_f32_16x16x32_bf16(ah[ot], bl, acc[ot][nt], 0, 0, 0);
        acc[ot][nt] = __builtin_amdgcn_mfma_f32_16x16x32_bf16(al[ot], bh, acc[ot][nt], 0, 0, 0);
      }
    }
  }
  __syncthreads();

  unsigned short* qT = (unsigned short*)smem;             // [64][136]
  unsigned short* vTl = (unsigned short*)(smem + 17408);  // [128][72]

#pragma unroll
  for (int ot = 0; ot < 4; ot++) {
#pragma unroll
    for (int r = 0; r < 4; r++) {
      const int o = wave * 64 + ot * 16 + lg * 4 + r;
      float A = gamma[o] * rsqrtf(var[o] + 1e-5f);
      float Bo = beta[o] + (b_inp[o] - mean[o]) * A;
#pragma unroll
      for (int nt = 0; nt < 4; nt++) {
        float val = acc[ot][nt][r] * A + Bo;
        unsigned short hv = f2bf(val);
        int n = nt * 16 + l15;
        if (wave < 2) {
          qT[n * 136 + o] = hv;
        } else {
          vTl[(o - 128) * 72 + n] = hv;
        }
      }
    }
  }
  __syncthreads();
  {
    int j = tid >> 2, c0 = (tid & 3) * 32;
    unsigned short* dst = q + ((size_t)b * N_TOK + n0 + j) * C_DIM + c0;
    const unsigned short* s = qT + j * 136 + c0;
#pragma unroll
    for (int i = 0; i < 32; i += 8) *(bf16x8*)(dst + i) = *(const bf16x8*)(s + i);
  }
  {
    int c = tid >> 1, h = (tid & 1) * 32;
    unsigned short* dst = vT + ((size_t)b * C_DIM + c) * N_TOK + n0 + h;
    const unsigned short* s = vTl + c * 72 + h;
#pragma unroll
    for (int i = 0; i < 32; i += 8) *(bf16x8*)(dst + i) = *(const bf16x8*)(s + i);
  }
  // ---- row-norm^2 max -> global atomic (for fixed-m softmax bound) ----
  {
    int row = tid >> 2, qn = tid & 3;
    const unsigned short* qr = qT + row * 136 + qn * 32;
    float s = 0.f;
#pragma unroll
    for (int i = 0; i < 32; i++) {
      float f = bf2f(qr[i]);
      s = fmaf(f, f, s);
    }
    s += __shfl_xor(s, 1);
    s += __shfl_xor(s, 2);
    if ((tid & 3) == 0) blkred[row] = s;
    __syncthreads();
    if (tid < 64) {
      float v = blkred[tid];
      v = fmaxf(v, __shfl_xor(v, 1));
      v = fmaxf(v, __shfl_xor(v, 2));
      v = fmaxf(v, __shfl_xor(v, 4));
      v = fmaxf(v, __shfl_xor(v, 8));
      v = fmaxf(v, __shfl_xor(v, 16));
      v = fmaxf(v, __shfl_xor(v, 32));
      if (tid == 0) atomicMax(m2bits, __float_as_int(v));
    }
  }
}

// ---------------- Stage 2: attention (fixed-m) + fused project_out ----------------
// r7 structure + PER-BLOCK COLUMN PHASE STAGGER: block bid processes K-tiles in
// order ktt=(kt+phase)&63, so concurrent blocks write atn across ALL column
// windows (full HBM channel spread) instead of lockstep on one window.
__global__ __launch_bounds__(256, 4) void attn_kernel(
    const unsigned short* __restrict__ q, const unsigned short* __restrict__ vT,
    const float* __restrict__ w_out, const float* __restrict__ b_out,
    float* __restrict__ yout, float* __restrict__ atn,
    const float* __restrict__ m2ptr) {
  __shared__ char smem[37888];
  // [0,32768): K dbuf (2 x 16KB); reused post-loop as yl/ol proj scratch
  // [32768,37376): pbuf [2][16][72] bf16
  // [37376,37632): statsL [64] f32

  const int tid = threadIdx.x;
  const int lane = tid & 63;
  const int kq = tid >> 6;  // wave = key-quarter for QK, channel-pair for PV
  const int l15 = lane & 15, lg = lane >> 4, l7 = lane & 7;
  const int bid = (int)((blockIdx.x & 7) * 128 + (blockIdx.x >> 3));
  const int b = bid >> 8;
  const int row0 = (bid & 255) << 4;
  const int phase = bid & 63;  // column-phase stagger

  const unsigned short* qb = q + (size_t)b * N_TOK * C_DIM;
  const unsigned short* vb = vT + (size_t)b * C_DIM * N_TOK;

  const float scale = 0.08838834764831845f;  // 1/sqrt(128)
  const float ke = scale * LOG2E;
  const float nmk = -(m2ptr[0]) * ke;

  bf16x8 qf[4];
#pragma unroll
  for (int ks = 0; ks < 4; ks++)
    qf[ks] = *(const bf16x8*)(qb + (size_t)(row0 + l15) * C_DIM + ks * 32 + lg * 8);

  int koff[4];
#pragma unroll
  for (int ks = 0; ks < 4; ks++) koff[ks] = (ks * 64 + lg * 16) ^ (l7 * 16);
  const int kqbase = kq * 4096 + l15 * 256;

  auto stageK = [&](int kt, int buf) {
    char* base = smem + buf * 16384;
#pragma unroll
    for (int i = 0; i < 4; i++) {
      int lin = i * 256 + tid;
      int key = lin >> 4;
      int c = ((lin & 15) * 8) ^ ((key & 7) * 8);
      gload_lds16(qb + (size_t)(kt * 64 + key) * C_DIM + c, base + lin * 16);
    }
  };

  unsigned short* pbw = (unsigned short*)(smem + 32768) + l15 * 72 + kq * 16 + lg * 4;
  const char* parb = smem + 32768 + l15 * 144;
  float* statsL = (float*)(smem + 37376);

  const unsigned short* vl0 = vb + (size_t)((kq * 2 + 0) * 16 + l15) * N_TOK + lg * 8;
  const unsigned short* vl1 = vb + (size_t)((kq * 2 + 1) * 16 + l15) * N_TOK + lg * 8;

  float lpart = 0.f;
  f32x4 yacc[2];
  yacc[0] = {0.f, 0.f, 0.f, 0.f};
  yacc[1] = {0.f, 0.f, 0.f, 0.f};

  bf16x8 vA[2][2], vB[2][2];
  // prologue: stage K(ktt of 0), load V(ktt of 0); full drain once
  stageK(phase, 0);
#pragma unroll
  for (int ks2 = 0; ks2 < 2; ks2++) {
    vA[0][ks2] = *(const bf16x8*)(vl0 + (size_t)phase * 64 + ks2 * 32);
    vA[1][ks2] = *(const bf16x8*)(vl1 + (size_t)phase * 64 + ks2 * 32);
  }
  WAIT_VM(0);
  SBAR();
  SCHED_FENCE();

  auto sweep1_iter = [&](int kt, bf16x8(&vc)[2][2], bf16x8(&vn)[2][2]) {
    // issue next tile's loads: exactly 8 VMEM ops per wave
    if (kt + 1 < 64) {
      const int kttn = (kt + 1 + phase) & 63;
      stageK(kttn, (kt + 1) & 1);
      const unsigned short* v0 = vl0 + (size_t)kttn * 64;
      const unsigned short* v1 = vl1 + (size_t)kttn * 64;
#pragma unroll
      for (int ks2 = 0; ks2 < 2; ks2++) {
        vn[0][ks2] = *(const bf16x8*)(v0 + ks2 * 32);
        vn[1][ks2] = *(const bf16x8*)(v1 + ks2 * 32);
      }
      WAIT_VM(8);  // waits for tile kt's 8 loads (issued last iter); keeps 8 in flight
    } else {
      WAIT_VM(0);
    }
    SBAR();  // tile kt staged for all waves
    SCHED_FENCE();
    const char* kb = smem + (kt & 1) * 16384;
    f32x4 acc = {0.f, 0.f, 0.f, 0.f};
#pragma unroll
    for (int ks = 0; ks < 4; ks++) {
      bf16x8 ak = *(const bf16x8*)(kb + kqbase + koff[ks]);
      acc = __builtin_amdgcn_mfma_f32_16x16x32_bf16(ak, qf[ks], acc, 0, 0, 0);
    }
    bf16x4 pk;
#pragma unroll
    for (int r = 0; r < 4; r++) {
      float p = __builtin_amdgcn_exp2f(fmaf(acc[r], ke, nmk));
      lpart += p;
      pk[r] = (short)f2bf(p);
    }
    *(bf16x4*)(pbw + (kt & 1) * 1152) = pk;
    WAIT_LGKM0;
    SBAR();  // P visible to all waves
    SCHED_FENCE();
    const char* pbt = parb + (kt & 1) * 2304;
#pragma unroll
    for (int ks2 = 0; ks2 < 2; ks2++) {
      bf16x8 ap = *(const bf16x8*)(pbt + ks2 * 64 + lg * 16);
      yacc[0] = __builtin_amdgcn_mfma_f32_16x16x32_bf16(ap, vc[0][ks2], yacc[0], 0, 0, 0);
      yacc[1] = __builtin_amdgcn_mfma_f32_16x16x32_bf16(ap, vc[1][ks2], yacc[1], 0, 0, 0);
    }
  };

  for (int kt = 0; kt < 64; kt += 2) {
    sweep1_iter(kt, vA, vB);
    sweep1_iter(kt + 1, vB, vA);
  }

  // ---- merge l across lanes and key-quarters ----
  lpart += __shfl_xor(lpart, 16);
  lpart += __shfl_xor(lpart, 32);
  if (lg == 0) statsL[kq * 16 + l15] = lpart;
  __syncthreads();

  float invl_r[4];
#pragma unroll
  for (int r = 0; r < 4; r++) {
    const int row = lg * 4 + r;
    invl_r[r] = 1.0f / (statsL[row] + statsL[16 + row] + statsL[32 + row] + statsL[48 + row]);
  }
  const float invl2 =
      1.0f / (statsL[l15] + statsL[16 + l15] + statsL[32 + l15] + statsL[48 + l15]);

  // ---- fused project_out (kbuf area as scratch) ----
  __syncthreads();
  {
    unsigned short* yl = (unsigned short*)smem;  // [16][136] bf16
    float* ol = (float*)(smem + 8192);           // [128][20] f32
#pragma unroll
    for (int ctl = 0; ctl < 2; ctl++)
#pragma unroll
      for (int r = 0; r < 4; r++)
        yl[(lg * 4 + r) * 136 + (kq * 2 + ctl) * 16 + l15] = f2bf(yacc[ctl][r] * invl_r[r]);
    __syncthreads();

    bf16x8 af[4];
#pragma unroll
    for (int ks = 0; ks < 4; ks++)
      af[ks] = *(const bf16x8*)(yl + l15 * 136 + ks * 32 + lg * 8);

#pragma unroll
    for (int cotl = 0; cotl < 2; cotl++) {
      const int cot = kq * 2 + cotl;
      f32x4 oacc = {0.f, 0.f, 0.f, 0.f};
#pragma unroll
      for (int ks = 0; ks < 4; ks++) {
        const float* wp = w_out + (cot * 16 + l15) * C_DIM + ks * 32 + lg * 8;
        float4 w0 = *(const float4*)wp;
        float4 w1 = *(const float4*)(wp + 4);
        bf16x8 bw;
#pragma unroll
        for (int e = 0; e < 8; e++) bw[e] = (short)f2bf((e < 4) ? (&w0.x)[e] : (&w1.x)[e - 4]);
        oacc = __builtin_amdgcn_mfma_f32_16x16x32_bf16(af[ks], bw, oacc, 0, 0, 0);
      }
      float bo = b_out[cot * 16 + l15];
#pragma unroll
      for (int r = 0; r < 4; r++) ol[(cot * 16 + l15) * 20 + lg * 4 + r] = oacc[r] + bo;
    }
    __syncthreads();
    {
      const int co = tid >> 1;
      const int r0 = (tid & 1) * 8;
      float* dst = yout + ((size_t)b * C_DIM + co) * N_TOK + row0 + r0;
      const float* s = ol + co * 20 + r0;
      *(float4*)dst = *(const float4*)s;
      *(float4*)(dst + 4) = *(const float4*)(s + 4);
    }
  }
  __syncthreads();  // scratch done before kbuf staging reuse

  // ---- Sweep 2: recompute S^T (staggered ktt), store atn = p'/l ----
  stageK(phase, 0);
  WAIT_VM(0);
  SBAR();
  SCHED_FENCE();
  float* atnp = atn + ((size_t)b * N_TOK + row0 + l15) * N_TOK + kq * 16 + lg * 4;
  for (int kt = 0; kt < 64; kt++) {
    const int ktt = (kt + phase) & 63;
    if (kt + 1 < 64) {
      stageK((kt + 1 + phase) & 63, (kt + 1) & 1);  // 4 VMEM
      WAIT_VM(5);  // waits tile kt's K loads; prev store stays in flight
    } else {
      WAIT_VM(1);
    }
    SBAR();
    SCHED_FENCE();
    const char* kb = smem + (kt & 1) * 16384;
    f32x4 acc = {0.f, 0.f, 0.f, 0.f};
#pragma unroll
    for (int ks = 0; ks < 4; ks++) {
      bf16x8 ak = *(const bf16x8*)(kb + kqbase + koff[ks]);
      acc = __builtin_amdgcn_mfma_f32_16x16x32_bf16(ak, qf[ks], acc, 0, 0, 0);
    }
    f32x4 o;
#pragma unroll
    for (int r = 0; r < 4; r++)
      o[r] = __builtin_amdgcn_exp2f(fmaf(acc[r], ke, nmk)) * invl2;
    *(f32x4*)(atnp + (size_t)ktt * 64) = o;
    SBAR();  // keep waves phase-locked so buf overwrite can't outrun slow readers
    SCHED_FENCE();
  }
}

extern "C" void kernel_launch(void* const* d_in, const int* in_sizes, int n_in,
                              void* d_out, int out_size, void* d_ws, size_t ws_size,
                              hipStream_t stream) {
  const float* x = (const float*)d_in[0];
  const float* w_inp = (const float*)d_in[1];
  const float* b_inp = (const float*)d_in[2];
  const float* gamma = (const float*)d_in[3];
  const float* beta = (const float*)d_in[4];
  const float* mean = (const float*)d_in[5];
  const float* var = (const float*)d_in[6];
  const float* w_out = (const float*)d_in[7];
  const float* b_out = (const float*)d_in[8];

  float* out = (float*)d_out;
  float* yout = out;                              // [4][128][4096]
  float* atn = out + (size_t)NB * C_DIM * N_TOK;  // [4][4096][4096]

  unsigned short* q = (unsigned short*)d_ws;            // [4][4096][128] bf16
  unsigned short* vT = q + (size_t)NB * N_TOK * C_DIM;  // [4][128][4096] bf16
  int* m2bits = (int*)(vT + (size_t)NB * C_DIM * N_TOK);

  hipMemsetAsync(m2bits, 0, 4, stream);
  proj_in_kernel<<<256, 256, 0, stream>>>(x, w_inp, b_inp, gamma, beta, mean, var, q, vT, m2bits);
  attn_kernel<<<1024, 256, 0, stream>>>(q, vT, w_out, b_out, yout, atn, (const float*)m2bits);
}

// Round 9
// 225.502 us; speedup vs baseline: 1.1114x; 1.0574x over previous
//
#include <hip/hip_runtime.h>
#include <stdint.h>
#include <math.h>

#define C_DIM 128
#define N_TOK 4096
#define NB 4
#define LOG2E 1.4426950408889634f

typedef __attribute__((ext_vector_type(8))) short bf16x8;
typedef __attribute__((ext_vector_type(4))) short bf16x4;
typedef __attribute__((ext_vector_type(4))) float f32x4;

#define WAIT_VM(N) asm volatile("s_waitcnt vmcnt(" #N ")" ::: "memory")
#define SBAR() __builtin_amdgcn_s_barrier()
#define SCHED_FENCE() __builtin_amdgcn_sched_barrier(0)

__device__ __forceinline__ unsigned short f2bf(float f) {
  unsigned u = __builtin_bit_cast(unsigned, f);
  unsigned r = (u + 0x7FFFu + ((u >> 16) & 1u)) >> 16;
  return (unsigned short)r;
}
__device__ __forceinline__ float bf2f(unsigned short h) {
  return __builtin_bit_cast(float, ((unsigned)h) << 16);
}
__device__ __forceinline__ void gload_lds16(const void* g, void* l) {
  __builtin_amdgcn_global_load_lds((const __attribute__((address_space(1))) void*)g,
                                   (__attribute__((address_space(3))) void*)l,
                                   16, 0, 0);
}

// ---------------- Stage 1: conv1x1(c->2c)+BN -> q [b][n][c] bf16, vT [b][c][n] bf16, max|q|^2 ----------------
__global__ __launch_bounds__(256) void proj_in_kernel(
    const float* __restrict__ x, const float* __restrict__ w_inp,
    const float* __restrict__ b_inp, const float* __restrict__ gamma,
    const float* __restrict__ beta, const float* __restrict__ mean,
    const float* __restrict__ var,
    unsigned short* __restrict__ q, unsigned short* __restrict__ vT,
    int* __restrict__ m2bits) {
  __shared__ char smem[36096];
  unsigned short* xh = (unsigned short*)smem;            // [64][136] bf16 hi
  unsigned short* xl = (unsigned short*)(smem + 17408);  // [64][136] bf16 lo
  float* blkred = (float*)(smem + 35840);                // [64]

  const int tid = threadIdx.x;
  const int b = blockIdx.x >> 6;
  const int n0 = (blockIdx.x & 63) << 6;
  const int lane = tid & 63;
  const int wave = tid >> 6;
  const int l15 = lane & 15, lg = lane >> 4;

  {
    const int c = tid >> 1;
    const int j0 = (tid & 1) * 32;
    const float* src = x + ((size_t)b * C_DIM + c) * N_TOK + n0 + j0;
#pragma unroll
    for (int j = 0; j < 32; j += 4) {
      float4 v4 = *(const float4*)(src + j);
#pragma unroll
      for (int e = 0; e < 4; e++) {
        float f = (&v4.x)[e];
        unsigned short hi = f2bf(f);
        unsigned short lo = f2bf(f - bf2f(hi));
        int n = j0 + j + e;
        xh[n * 136 + c] = hi;
        xl[n * 136 + c] = lo;
      }
    }
  }
  __syncthreads();

  f32x4 acc[4][4];
#pragma unroll
  for (int i = 0; i < 4; i++)
#pragma unroll
    for (int j = 0; j < 4; j++) acc[i][j] = {0.f, 0.f, 0.f, 0.f};

#pragma unroll
  for (int ks = 0; ks < 4; ks++) {
    bf16x8 ah[4], al[4];
#pragma unroll
    for (int ot = 0; ot < 4; ot++) {
      const int o = wave * 64 + ot * 16 + l15;
      const float* wp = w_inp + o * C_DIM + ks * 32 + lg * 8;
      float4 w0 = *(const float4*)wp;
      float4 w1 = *(const float4*)(wp + 4);
#pragma unroll
      for (int e = 0; e < 8; e++) {
        float f = (e < 4) ? (&w0.x)[e] : (&w1.x)[e - 4];
        unsigned short hi = f2bf(f);
        ah[ot][e] = (short)hi;
        al[ot][e] = (short)f2bf(f - bf2f(hi));
      }
    }
#pragma unroll
    for (int nt = 0; nt < 4; nt++) {
      const int off = (nt * 16 + l15) * 136 + ks * 32 + lg * 8;
      bf16x8 bh = *(const bf16x8*)(xh + off);
      bf16x8 bl = *(const bf16x8*)(xl + off);
#pragma unroll
      for (int ot = 0; ot < 4; ot++) {
        acc[ot][nt] = __builtin_amdgcn_mfma_f32_16x16x32_bf16(ah[ot], bh, acc[ot][nt], 0, 0, 0);
        acc[ot][nt] = __builtin_amdgcn_mfma_f32_16x16x32_bf16(ah[ot], bl, acc[ot][nt], 0, 0, 0);
        acc[ot][nt] = __builtin_amdgcn_mfma_f32_16x16x32_bf16(al[ot], bh, acc[ot][nt], 0, 0, 0);
      }
    }
  }
  __syncthreads();

  unsigned short* qT = (unsigned short*)smem;             // [64][136]
  unsigned short* vTl = (unsigned short*)(smem + 17408);  // [128][72]

#pragma unroll
  for (int ot = 0; ot < 4; ot++) {
#pragma unroll
    for (int r = 0; r < 4; r++) {
      const int o = wave * 64 + ot * 16 + lg * 4 + r;
      float A = gamma[o] * rsqrtf(var[o] + 1e-5f);
      float Bo = beta[o] + (b_inp[o] - mean[o]) * A;
#pragma unroll
      for (int nt = 0; nt < 4; nt++) {
        float val = acc[ot][nt][r] * A + Bo;
        unsigned short hv = f2bf(val);
        int n = nt * 16 + l15;
        if (wave < 2) {
          qT[n * 136 + o] = hv;
        } else {
          vTl[(o - 128) * 72 + n] = hv;
        }
      }
    }
  }
  __syncthreads();
  {
    int j = tid >> 2, c0 = (tid & 3) * 32;
    unsigned short* dst = q + ((size_t)b * N_TOK + n0 + j) * C_DIM + c0;
    const unsigned short* s = qT + j * 136 + c0;
#pragma unroll
    for (int i = 0; i < 32; i += 8) *(bf16x8*)(dst + i) = *(const bf16x8*)(s + i);
  }
  {
    int c = tid >> 1, h = (tid & 1) * 32;
    unsigned short* dst = vT + ((size_t)b * C_DIM + c) * N_TOK + n0 + h;
    const unsigned short* s = vTl + c * 72 + h;
#pragma unroll
    for (int i = 0; i < 32; i += 8) *(bf16x8*)(dst + i) = *(const bf16x8*)(s + i);
  }
  // ---- row-norm^2 max -> global atomic (fixed-m softmax bound) ----
  {
    int row = tid >> 2, qn = tid & 3;
    const unsigned short* qr = qT + row * 136 + qn * 32;
    float s = 0.f;
#pragma unroll
    for (int i = 0; i < 32; i++) {
      float f = bf2f(qr[i]);
      s = fmaf(f, f, s);
    }
    s += __shfl_xor(s, 1);
    s += __shfl_xor(s, 2);
    if ((tid & 3) == 0) blkred[row] = s;
    __syncthreads();
    if (tid < 64) {
      float v = blkred[tid];
      v = fmaxf(v, __shfl_xor(v, 1));
      v = fmaxf(v, __shfl_xor(v, 2));
      v = fmaxf(v, __shfl_xor(v, 4));
      v = fmaxf(v, __shfl_xor(v, 8));
      v = fmaxf(v, __shfl_xor(v, 16));
      v = fmaxf(v, __shfl_xor(v, 32));
      if (tid == 0) atomicMax(m2bits, __float_as_int(v));
    }
  }
}

// ---------------- Kernel A: flash pass (l + PV + project_out), no atn traffic ----------------
// 512 blocks x 32 q-rows, 4 waves = 2 rg x 2 kh. Wave-private P (no cross-wave
// exchange in loop). ONE barrier/iter; stage issued AFTER barrier (race-free);
// counted WAIT_VM(8). Emits y and invl[b][n].
__global__ __launch_bounds__(256, 2) void attn_pv_kernel(
    const unsigned short* __restrict__ q, const unsigned short* __restrict__ vT,
    const float* __restrict__ w_out, const float* __restrict__ b_out,
    float* __restrict__ yout, float* __restrict__ invlw,
    const float* __restrict__ m2ptr) {
  __shared__ char smem[55552];
  // [0,32768): K dbuf (2x16KB); post-loop reused as yl/ol scratch
  // [32768,37888): per-wave P [16][40] bf16; [37888,38144): statsL; [38144,55552): ymergeF

  const int tid = threadIdx.x;
  const int lane = tid & 63;
  const int wave = tid >> 6;
  const int rg = wave >> 1;
  const int kh = wave & 1;
  const int l15 = lane & 15, lg = lane >> 4, l7 = lane & 7;
  const int bid = (int)((blockIdx.x & 7) * 64 + (blockIdx.x >> 3));
  const int b = bid >> 7;
  const int q0 = (bid & 127) << 5;
  const int row0 = q0 + rg * 16;

  const unsigned short* qb = q + (size_t)b * N_TOK * C_DIM;
  const unsigned short* vb = vT + (size_t)b * C_DIM * N_TOK;

  const float scale = 0.08838834764831845f;
  const float ke = scale * LOG2E;
  const float nmk = -(m2ptr[0]) * ke;

  bf16x8 qf[4];
#pragma unroll
  for (int ks = 0; ks < 4; ks++)
    qf[ks] = *(const bf16x8*)(qb + (size_t)(row0 + l15) * C_DIM + ks * 32 + lg * 8);

  int koff[4];
#pragma unroll
  for (int ks = 0; ks < 4; ks++) koff[ks] = (ks * 64 + lg * 16) ^ (l7 * 16);
  const int krow = l15 * 256;

  auto stageK = [&](int kt, int buf) {
    char* base = smem + buf * 16384;
#pragma unroll
    for (int i = 0; i < 4; i++) {
      int lin = i * 256 + tid;
      int key = lin >> 4;
      int c = ((lin & 15) * 8) ^ ((key & 7) * 8);
      gload_lds16(qb + (size_t)(kt * 64 + key) * C_DIM + c, base + lin * 16);
    }
  };

  unsigned short* pbuf = (unsigned short*)(smem + 32768 + wave * 1280);  // [16][40]
  float* statsL = (float*)(smem + 37888);
  float* ymergeF = (float*)(smem + 38144);

  const unsigned short* vlane = vb + (size_t)l15 * N_TOK + kh * 32 + lg * 8;

  float lpart = 0.f;
  f32x4 yacc[8];
#pragma unroll
  for (int ct = 0; ct < 8; ct++) yacc[ct] = {0.f, 0.f, 0.f, 0.f};

  bf16x8 vA[8], vB[8];
  stageK(0, 0);
#pragma unroll
  for (int ct = 0; ct < 8; ct++) vA[ct] = *(const bf16x8*)(vlane + (size_t)ct * 16 * N_TOK);

  unsigned short* pbw0 = pbuf + l15 * 40 + lg * 4;
  unsigned short* pbw1 = pbuf + l15 * 40 + 16 + lg * 4;
  const unsigned short* par = pbuf + l15 * 40 + lg * 8;

  auto sweep1_iter = [&](int kt, bf16x8(&vc)[8], bf16x8(&vn)[8]) {
    WAIT_VM(8);  // stage(kt) (oldest 4 of last iter's 12) complete
    SBAR();      // all waves consumed buf^1 (reads of iter kt-1 done)
    SCHED_FENCE();
    if (kt + 1 < 64) {
      stageK(kt + 1, (kt + 1) & 1);  // 4 VMEM -> buf^1 (now safe)
      const unsigned short* vp = vlane + (size_t)(kt + 1) * 64;
#pragma unroll
      for (int ct = 0; ct < 8; ct++) vn[ct] = *(const bf16x8*)(vp + (size_t)ct * 16 * N_TOK);
    }
    SCHED_FENCE();
    const char* kb = smem + (kt & 1) * 16384;
#pragma unroll
    for (int nt = 0; nt < 2; nt++) {
      f32x4 acc = {0.f, 0.f, 0.f, 0.f};
#pragma unroll
      for (int ks = 0; ks < 4; ks++) {
        bf16x8 ak = *(const bf16x8*)(kb + (kh * 2 + nt) * 4096 + krow + koff[ks]);
        acc = __builtin_amdgcn_mfma_f32_16x16x32_bf16(ak, qf[ks], acc, 0, 0, 0);
      }
      bf16x4 pk;
#pragma unroll
      for (int r = 0; r < 4; r++) {
        float p = __builtin_amdgcn_exp2f(fmaf(acc[r], ke, nmk));
        lpart += p;
        pk[r] = (short)f2bf(p);
      }
      *(bf16x4*)(nt ? pbw1 : pbw0) = pk;
    }
    bf16x8 ap = *(const bf16x8*)par;
#pragma unroll
    for (int ct = 0; ct < 8; ct++)
      yacc[ct] = __builtin_amdgcn_mfma_f32_16x16x32_bf16(ap, vc[ct], yacc[ct], 0, 0, 0);
  };

  for (int kt = 0; kt < 64; kt += 2) {
    sweep1_iter(kt, vA, vB);
    sweep1_iter(kt + 1, vB, vA);
  }
  WAIT_VM(0);

  // ---- merge l; write invl ----
  lpart += __shfl_xor(lpart, 16);
  lpart += __shfl_xor(lpart, 32);
  if (lg == 0) statsL[kh * 32 + rg * 16 + l15] = lpart;
  __syncthreads();

  if (tid < 32) invlw[(size_t)b * N_TOK + q0 + tid] = 1.0f / (statsL[tid] + statsL[32 + tid]);

  float invl_r[4];
#pragma unroll
  for (int r = 0; r < 4; r++) {
    const int row = lg * 4 + r;
    invl_r[r] = 1.0f / (statsL[rg * 16 + row] + statsL[32 + rg * 16 + row]);
  }

  // ---- merge PV across kh, fused project_out ----
  if (kh) {
#pragma unroll
    for (int ct = 0; ct < 8; ct++)
#pragma unroll
      for (int r = 0; r < 4; r++)
        ymergeF[(rg * 16 + lg * 4 + r) * 136 + ct * 16 + l15] = yacc[ct][r];
  }
  __syncthreads();
  if (!kh) {
#pragma unroll
    for (int ct = 0; ct < 8; ct++)
#pragma unroll
      for (int r = 0; r < 4; r++)
        yacc[ct][r] = (yacc[ct][r] + ymergeF[(rg * 16 + lg * 4 + r) * 136 + ct * 16 + l15]) * invl_r[r];

    unsigned short* yl = (unsigned short*)(smem + rg * 16384);  // [16][136]
    float* ol = (float*)(smem + rg * 16384 + 4608);             // [128][20]
#pragma unroll
    for (int ct = 0; ct < 8; ct++)
#pragma unroll
      for (int r = 0; r < 4; r++)
        yl[(lg * 4 + r) * 136 + ct * 16 + l15] = f2bf(yacc[ct][r]);

    bf16x8 af[4];
#pragma unroll
    for (int ks = 0; ks < 4; ks++)
      af[ks] = *(const bf16x8*)(yl + l15 * 136 + ks * 32 + lg * 8);

#pragma unroll
    for (int cot = 0; cot < 8; cot++) {
      f32x4 oacc = {0.f, 0.f, 0.f, 0.f};
#pragma unroll
      for (int ks = 0; ks < 4; ks++) {
        const float* wp = w_out + (cot * 16 + l15) * C_DIM + ks * 32 + lg * 8;
        float4 w0 = *(const float4*)wp;
        float4 w1 = *(const float4*)(wp + 4);
        bf16x8 bw;
#pragma unroll
        for (int e = 0; e < 8; e++) bw[e] = (short)f2bf((e < 4) ? (&w0.x)[e] : (&w1.x)[e - 4]);
        oacc = __builtin_amdgcn_mfma_f32_16x16x32_bf16(af[ks], bw, oacc, 0, 0, 0);
      }
      float bo = b_out[cot * 16 + l15];
#pragma unroll
      for (int r = 0; r < 4; r++) ol[(cot * 16 + l15) * 20 + lg * 4 + r] = oacc[r] + bo;
    }
#pragma unroll
    for (int i = 0; i < 2; i++) {
      int co = i * 64 + lane;
      float* dst = yout + ((size_t)b * C_DIM + co) * N_TOK + row0;
      const float* s = ol + co * 20;
#pragma unroll
      for (int jj = 0; jj < 16; jj += 4) *(float4*)(dst + jj) = *(const float4*)(s + jj);
    }
  }
}

// ---------------- Kernel B: atn writer -- 128x128 tile GEMM, no loop/barrier churn ----------------
// atn[b][n][m] = exp2(ke*(q_n . q_m) + nmk) * invl[b][n]. 4096 blocks, 4 waves,
// 2 blocks/CU. Stage Q-tile + K-tile once (1 barrier), 64 MFMA/wave, store 16KB/wave.
__global__ __launch_bounds__(256, 2) void atn_write_kernel(
    const unsigned short* __restrict__ q, const float* __restrict__ invl,
    float* __restrict__ atn, const float* __restrict__ m2ptr) {
  __shared__ char smem[65536];  // [0,32K) Q-tile [128][128] swz; [32K,64K) K-tile

  const int tid = threadIdx.x;
  const int lane = tid & 63;
  const int wv = tid >> 6;
  const int l15 = lane & 15, lg = lane >> 4, l7 = lane & 7;
  const int bid = (int)((blockIdx.x & 7) * 512 + (blockIdx.x >> 3));
  const int b = bid >> 10;
  const int rem = bid & 1023;
  const int n0 = ((rem >> 5) & 31) << 7;
  const int m0 = (rem & 31) << 7;

  const unsigned short* qb = q + (size_t)b * N_TOK * C_DIM;
  const float ke = 0.08838834764831845f * LOG2E;
  const float nmk = -(m2ptr[0]) * ke;

#pragma unroll
  for (int i = 0; i < 8; i++) {
    int lin = i * 256 + tid;
    int row = lin >> 4;
    int c = ((lin & 15) * 8) ^ ((row & 7) * 8);
    gload_lds16(qb + (size_t)(n0 + row) * C_DIM + c, smem + lin * 16);
  }
#pragma unroll
  for (int i = 0; i < 8; i++) {
    int lin = i * 256 + tid;
    int row = lin >> 4;
    int c = ((lin & 15) * 8) ^ ((row & 7) * 8);
    gload_lds16(qb + (size_t)(m0 + row) * C_DIM + c, smem + 32768 + lin * 16);
  }

  float iv[8];
#pragma unroll
  for (int nt = 0; nt < 8; nt++) iv[nt] = invl[(size_t)b * N_TOK + n0 + nt * 16 + l15];

  WAIT_VM(0);
  SBAR();

  int koff[4];
#pragma unroll
  for (int ks = 0; ks < 4; ks++) koff[ks] = (ks * 64 + lg * 16) ^ (l7 * 16);
  const char* qt = smem;
  const char* ktl = smem + 32768;
  const int wm = wv * 32;

  bf16x8 am[2][4];
#pragma unroll
  for (int mt = 0; mt < 2; mt++)
#pragma unroll
    for (int ks = 0; ks < 4; ks++)
      am[mt][ks] = *(const bf16x8*)(ktl + (wm + mt * 16 + l15) * 256 + koff[ks]);

  float* atnb = atn + ((size_t)b * N_TOK + n0) * N_TOK + m0 + wm;

#pragma unroll
  for (int nt = 0; nt < 8; nt++) {
    bf16x8 bq[4];
#pragma unroll
    for (int ks = 0; ks < 4; ks++)
      bq[ks] = *(const bf16x8*)(qt + (nt * 16 + l15) * 256 + koff[ks]);
    f32x4 acc0 = {0.f, 0.f, 0.f, 0.f};
    f32x4 acc1 = {0.f, 0.f, 0.f, 0.f};
#pragma unroll
    for (int ks = 0; ks < 4; ks++) {
      acc0 = __builtin_amdgcn_mfma_f32_16x16x32_bf16(am[0][ks], bq[ks], acc0, 0, 0, 0);
      acc1 = __builtin_amdgcn_mfma_f32_16x16x32_bf16(am[1][ks], bq[ks], acc1, 0, 0, 0);
    }
    float* rowp = atnb + (size_t)(nt * 16 + l15) * N_TOK + lg * 4;
    f32x4 o0, o1;
#pragma unroll
    for (int r = 0; r < 4; r++) {
      o0[r] = __builtin_amdgcn_exp2f(fmaf(acc0[r], ke, nmk)) * iv[nt];
      o1[r] = __builtin_amdgcn_exp2f(fmaf(acc1[r], ke, nmk)) * iv[nt];
    }
    *(f32x4*)rowp = o0;
    *(f32x4*)(rowp + 16) = o1;
  }
}

extern "C" void kernel_launch(void* const* d_in, const int* in_sizes, int n_in,
                              void* d_out, int out_size, void* d_ws, size_t ws_size,
                              hipStream_t stream) {
  const float* x = (const float*)d_in[0];
  const float* w_inp = (const float*)d_in[1];
  const float* b_inp = (const float*)d_in[2];
  const float* gamma = (const float*)d_in[3];
  const float* beta = (const float*)d_in[4];
  const float* mean = (const float*)d_in[5];
  const float* var = (const float*)d_in[6];
  const float* w_out = (const float*)d_in[7];
  const float* b_out = (const float*)d_in[8];

  float* out = (float*)d_out;
  float* yout = out;                              // [4][128][4096]
  float* atn = out + (size_t)NB * C_DIM * N_TOK;  // [4][4096][4096]

  unsigned short* q = (unsigned short*)d_ws;            // [4][4096][128] bf16
  unsigned short* vT = q + (size_t)NB * N_TOK * C_DIM;  // [4][128][4096] bf16
  char* after = (char*)(vT + (size_t)NB * C_DIM * N_TOK);
  int* m2bits = (int*)after;
  float* invlw = (float*)(after + 256);  // [4][4096] f32

  hipMemsetAsync(m2bits, 0, 4, stream);
  proj_in_kernel<<<256, 256, 0, stream>>>(x, w_inp, b_inp, gamma, beta, mean, var, q, vT, m2bits);
  attn_pv_kernel<<<512, 256, 0, stream>>>(q, vT, w_out, b_out, yout, invlw, (const float*)m2bits);
  atn_write_kernel<<<4096, 256, 0, stream>>>(q, invlw, atn, (const float*)m2bits);
}